// Round 4
// baseline (255.653 us; speedup 1.0000x reference)
//
#include <hip/hip_runtime.h>
#include <hip/hip_bf16.h>

// Established facts (R1..R10 on HW):
//  - Harness I/O is FP32; large fixed harness overhead (512MB workspace re-poison
//    fills at ~77us @86% HBM peak dominate rocprof top-5; our kernels never appear).
//  - MFMA 16x16x32_bf16 layouts verified in-harness:
//      A[m=lane&15][k=(lane>>4)*8+j], B[n=lane&15][k=(lane>>4)*8+j],
//      C/D col=lane&15, row=(lane>>4)*4+reg.
//  - R9: barrier restructure (5->2 per tile): NO change. Node loop is HBM-paced.
//  - R10: prep-kernel deletion (3->2 launches): NO change. Launch-count theory dead.
//  - R11: fully fused single kernel (below). Bench attempt hit
//    GPUAcquisitionTimeout (infra, no measurement) — resubmitting unchanged.
//    Pre-commit: if dur_us is within noise of 248.9, declare ROOFLINE.

#define G_   4096
#define NPG_ 32
#define NN_  (G_*NPG_)     // 131072
#define D_   256
#define SH_  256
#define HDG_ 50
#define HDN_ 3

// output layout (fp32 elements): g_head | n_head | g_var | n_var
#define OFF_GH 0
#define OFF_NH (G_*HDG_)             // 204800
#define OFF_GV (OFF_NH + NN_*HDN_)   // 598016
#define OFF_NV (OFF_GV + G_*HDG_)    // 802816

typedef short v8s __attribute__((ext_vector_type(8)));   // 8 bf16 = 16 B (MFMA A/B frag)
typedef short v4s __attribute__((ext_vector_type(4)));
typedef float v4f __attribute__((ext_vector_type(4)));   // MFMA C/D frag

__device__ __forceinline__ unsigned short f2bfu(float v) {
    __hip_bfloat16 b = __float2bfloat16(v);
    return *reinterpret_cast<unsigned short*>(&b);
}

#define MFMA16(a, b, c) __builtin_amdgcn_mfma_f32_16x16x32_bf16((a), (b), (c), 0, 0, 0)

// ---- single fused kernel: 256 blocks x 512 threads (8 waves), branch = blockIdx&1.
// Startup: prefix-scan dsname -> block's <=16 (tile,pair) graph ids; self-load
//   node-MLP weights (B1/B2) from fp32.
// Main loop: 2-graph 64-row tiles, 2 barriers/tile; graph means -> LDS (xgl).
// Tail: block-local 2-layer graph MLP over its <=32 graphs (M=32, MFMA),
//   weights gathered from L2-resident fp32 Wgs/Wgh into the SAME B1/B2 regs. ----
__global__ __launch_bounds__(512) void fused_all(const float* __restrict__ x,
                                                 const int* __restrict__ dsname,
                                                 const float* __restrict__ Wn1,
                                                 const float* __restrict__ bn1,
                                                 const float* __restrict__ Wn2,
                                                 const float* __restrict__ bn2,
                                                 const float* __restrict__ Wgs,
                                                 const float* __restrict__ bgs,
                                                 const float* __restrict__ Wgh,
                                                 const float* __restrict__ bgh,
                                                 float* __restrict__ out) {
    __shared__ __align__(16) unsigned short xs[64 * 264];   // 33.8 KB bf16 x-tile
    __shared__ __align__(16) unsigned short hs[64 * 264];   // 33.8 KB bf16 hidden (reused by tail)
    __shared__ __align__(16) float red[16 * 256];           // 16 KB mean partials
    __shared__ __align__(16) unsigned short xgl[32 * 264];  // 16.9 KB block's graph means
    __shared__ int glds[32];                                // up to 16 tiles x 2 graph ids
    __shared__ int scanS[10];                               // [0..7] wave bases, [8] cnt, [9] last graph
    const int t = threadIdx.x;
    const int wave = t >> 6, lane = t & 63;
    const int l15 = lane & 15, quad = lane >> 4;
    const int br = blockIdx.x & 1;
    const int bslot = blockIdx.x >> 1;        // 0..127

    // ---- (a) per-block branch list: prefix scan of dsname ----
    int pre, c0;
    {
        c0 = 0;
        #pragma unroll
        for (int k = 0; k < 8; k++) c0 += (dsname[t * 8 + k] == br) ? 1 : 0;
        pre = c0;
        #pragma unroll
        for (int d = 1; d < 64; d <<= 1) {
            const int o = __shfl_up(pre, d);
            if (lane >= d) pre += o;
        }
        if (lane == 63) scanS[wave] = pre;    // wave inclusive totals
    }
    __syncthreads();
    if (t == 0) {
        int s = 0;
        #pragma unroll
        for (int w = 0; w < 8; w++) { const int v = scanS[w]; scanS[w] = s; s += v; }
        scanS[8] = s;                         // cnt for this branch
    }
    __syncthreads();
    const int cnt = scanS[8];
    const int ntile = (cnt + 1) >> 1;
    {
        int slot = scanS[wave] + (pre - c0);  // exclusive base for this thread
        for (int k = 0; k < 8; k++) {
            const int g = t * 8 + k;
            if (dsname[g] == br) {
                const int ti2 = slot >> 1;
                const int q = ti2 - bslot;
                if (q >= 0 && (q & 127) == 0 && (q >> 7) < 16)
                    glds[(q >> 7) * 2 + (slot & 1)] = g;
                if (slot == cnt - 1) scanS[9] = g;   // last graph (odd-cnt clamp)
                slot++;
            }
        }
    }
    __syncthreads();

    // ---- (b) self-load node-MLP B1/B2/biases from fp32 (Wn1 512KB, L2-hot) ----
    const int base_n = (wave & 1) * 128 + (wave >> 1) * 32;
    v8s B1[2][8];
    float bias1[2];
    #pragma unroll
    for (int nt = 0; nt < 2; nt++) {
        const int s = base_n + nt * 16 + l15;
        const float* wp = Wn1 + br * 65536 + s;          // + d*256
        #pragma unroll
        for (int kt = 0; kt < 8; kt++) {
            v8s f;
            #pragma unroll
            for (int j = 0; j < 8; j++)
                f[j] = (short)f2bfu(wp[(kt * 32 + quad * 8 + j) * 256]);
            B1[nt][kt] = f;
        }
        bias1[nt] = bn1[br * 256 + s];
    }
    v8s B2[8];
    #pragma unroll
    for (int kt = 0; kt < 8; kt++) {
        v8s f;
        #pragma unroll
        for (int j = 0; j < 8; j++) {
            const int k = kt * 32 + quad * 8 + j;
            f[j] = (l15 < 6) ? (short)f2bfu(Wn2[br * 1536 + k * 6 + l15]) : (short)0;
        }
        B2[kt] = f;
    }
    float bias2 = 0.f;
    if (l15 < 6) bias2 = bn2[br * 6 + l15];

    // load mapping: thread t covers row r0+8k (k=0..7), dword cols colb..colb+3.
    const int r0 = t >> 6;           // 0..7 (== wave)
    const int colb = (t & 63) * 4;   // 0..252

    float4 pv[8];
    int ga = 0, gb = 0;
    if (bslot < ntile) {
        ga = glds[0];
        gb = (2 * bslot + 1 < cnt) ? glds[1] : scanS[9];
        const float* xa = x + (size_t)ga * 8192 + r0 * 256 + colb;
        const float* xb = x + (size_t)gb * 8192 + r0 * 256 + colb;
        #pragma unroll
        for (int k = 0; k < 4; k++) {
            pv[k]     = *(const float4*)(xa + k * 2048);
            pv[4 + k] = *(const float4*)(xb + k * 2048);
        }
    }

    for (int ti = bslot; ti < ntile; ti += 128) {
        const int gA = ga, gB = gb;
        const int lt = (ti - bslot) >> 7;    // local tile index 0..15

        // 1) convert pv -> xs (bf16) + fp32 mean partials -> red
        float4 sa = make_float4(0.f, 0.f, 0.f, 0.f);
        float4 sb = make_float4(0.f, 0.f, 0.f, 0.f);
        #pragma unroll
        for (int k = 0; k < 4; k++) {
            const float4 va = pv[k], vb = pv[4 + k];
            sa.x += va.x; sa.y += va.y; sa.z += va.z; sa.w += va.w;
            sb.x += vb.x; sb.y += vb.y; sb.z += vb.z; sb.w += vb.w;
            v4s bva, bvb;
            bva[0] = (short)f2bfu(va.x); bva[1] = (short)f2bfu(va.y);
            bva[2] = (short)f2bfu(va.z); bva[3] = (short)f2bfu(va.w);
            bvb[0] = (short)f2bfu(vb.x); bvb[1] = (short)f2bfu(vb.y);
            bvb[2] = (short)f2bfu(vb.z); bvb[3] = (short)f2bfu(vb.w);
            *(v4s*)(&xs[(r0 + 8 * k) * 264 + colb])      = bva;
            *(v4s*)(&xs[(32 + r0 + 8 * k) * 264 + colb]) = bvb;
        }
        *(float4*)(&red[r0 * 256 + colb])       = sa;
        *(float4*)(&red[(8 + r0) * 256 + colb]) = sb;

        // 2) prefetch NEXT tile (hidden under MFMA phase); skip dead last fetch
        {
            const int tn = ti + 128;
            if (tn < ntile) {
                const int ix = (tn - bslot) >> 7;   // 1..15
                ga = glds[ix * 2];
                gb = (2 * tn + 1 < cnt) ? glds[ix * 2 + 1] : scanS[9];
                const float* xa = x + (size_t)ga * 8192 + r0 * 256 + colb;
                const float* xb = x + (size_t)gb * 8192 + r0 * 256 + colb;
                #pragma unroll
                for (int k = 0; k < 4; k++) {
                    pv[k]     = *(const float4*)(xa + k * 2048);
                    pv[4 + k] = *(const float4*)(xb + k * 2048);
                }
            }
        }
        __syncthreads();   // A: xs + red visible

        // 3) mean -> xgl (LDS, stays in-block; no global xg)
        {
            const int g = t >> 8, c = t & 255;
            float m = 0.f;
            #pragma unroll
            for (int r = 0; r < 8; r++) m += red[(g * 8 + r) * 256 + c];
            xgl[(lt * 2 + g) * 264 + c] = f2bfu(m * (1.0f / NPG_));
        }

        // 4) L1 MFMA: M=64 (4 m-tiles), wave's N=32 (2 n-tiles), K=256; B in regs
        v4f acc[4][2];
        #pragma unroll
        for (int mt = 0; mt < 4; mt++)
            #pragma unroll
            for (int nt = 0; nt < 2; nt++) acc[mt][nt] = (v4f){0.f, 0.f, 0.f, 0.f};
        #pragma unroll
        for (int kt = 0; kt < 8; kt++) {
            const int ko = kt * 32 + quad * 8;
            v8s a0 = *(const v8s*)(&xs[(     l15) * 264 + ko]);
            v8s a1 = *(const v8s*)(&xs[(16 + l15) * 264 + ko]);
            v8s a2 = *(const v8s*)(&xs[(32 + l15) * 264 + ko]);
            v8s a3 = *(const v8s*)(&xs[(48 + l15) * 264 + ko]);
            #pragma unroll
            for (int nt = 0; nt < 2; nt++) {
                acc[0][nt] = MFMA16(a0, B1[nt][kt], acc[0][nt]);
                acc[1][nt] = MFMA16(a1, B1[nt][kt], acc[1][nt]);
                acc[2][nt] = MFMA16(a2, B1[nt][kt], acc[2][nt]);
                acc[3][nt] = MFMA16(a3, B1[nt][kt], acc[3][nt]);
            }
        }

        // 5) bias + ReLU -> hs (bf16)
        #pragma unroll
        for (int nt = 0; nt < 2; nt++) {
            const int col = base_n + nt * 16 + l15;
            #pragma unroll
            for (int mt = 0; mt < 4; mt++)
                #pragma unroll
                for (int r = 0; r < 4; r++) {
                    const int row = mt * 16 + quad * 4 + r;
                    const float v = acc[mt][nt][r] + bias1[nt];
                    hs[row * 264 + col] = f2bfu(v > 0.f ? v : 0.f);
                }
        }
        __syncthreads();   // C: hs complete; red/xs free for next tile

        // 6) L2 MFMA: waves 0..3 each own rows wave*16..+15, full K=256, direct stores.
        if (wave < 4) {
            v4f a2 = (v4f){0.f, 0.f, 0.f, 0.f};
            #pragma unroll
            for (int kt = 0; kt < 8; kt++) {
                v8s av = *(const v8s*)(&hs[(wave * 16 + l15) * 264 + kt * 32 + quad * 8]);
                a2 = MFMA16(av, B2[kt], a2);
            }
            if (l15 < 6) {
                #pragma unroll
                for (int r = 0; r < 4; r++) {
                    const int row = wave * 16 + quad * 4 + r;
                    const int g = (row < 32) ? gA : gB;
                    const int n = g * NPG_ + (row & 31);
                    const float v = a2[r] + bias2;
                    if (l15 < HDN_) out[OFF_NH + n * HDN_ + l15] = v;
                    else            out[OFF_NV + n * HDN_ + (l15 - HDN_)] = v * v;
                }
            }
        }
        // no trailing barrier: next hs writes happen only after next barrier A.
    }

    // ---- tail: block-local graph MLP over this block's <=32 graphs ----
    const int ntl = (ntile > bslot) ? ((ntile - 1 - bslot) / 128 + 1) : 0;  // tiles owned
    const int ngr = ntl * 2;                                               // rows valid
    if (ngr > 0) {
        __syncthreads();   // xgl writes visible; last L2's hs reads drained

        // reload B1 <- Wgs (same [256][256] shape/pattern as Wn1), bias1 <- bgs
        #pragma unroll
        for (int nt = 0; nt < 2; nt++) {
            const int s = base_n + nt * 16 + l15;
            const float* wp = Wgs + br * 65536 + s;
            #pragma unroll
            for (int kt = 0; kt < 8; kt++) {
                v8s f;
                #pragma unroll
                for (int j = 0; j < 8; j++)
                    f[j] = (short)f2bfu(wp[(kt * 32 + quad * 8 + j) * 256]);
                B1[nt][kt] = f;
            }
            bias1[nt] = bgs[br * 256 + s];
        }
        // reload B2 <- Wgh: wave's 16 output cols c2 = wave*16 + l15 (128 padded, 100 valid)
        const int c2 = wave * 16 + l15;
        #pragma unroll
        for (int kt = 0; kt < 8; kt++) {
            v8s f;
            #pragma unroll
            for (int j = 0; j < 8; j++) {
                const int k = kt * 32 + quad * 8 + j;
                f[j] = (c2 < 100) ? (short)f2bfu(Wgh[br * 25600 + k * 100 + c2]) : (short)0;
            }
            B2[kt] = f;
        }
        const float bias2g = (c2 < 100) ? bgh[br * 100 + c2] : 0.f;

        // layer 1: M=32 (2 m-tiles), wave N=32, K=256; A from xgl
        v4f acg[2][2];
        #pragma unroll
        for (int mt = 0; mt < 2; mt++)
            #pragma unroll
            for (int nt = 0; nt < 2; nt++) acg[mt][nt] = (v4f){0.f, 0.f, 0.f, 0.f};
        #pragma unroll
        for (int kt = 0; kt < 8; kt++) {
            const int ko = kt * 32 + quad * 8;
            v8s a0 = *(const v8s*)(&xgl[(     l15) * 264 + ko]);
            v8s a1 = *(const v8s*)(&xgl[(16 + l15) * 264 + ko]);
            #pragma unroll
            for (int nt = 0; nt < 2; nt++) {
                acg[0][nt] = MFMA16(a0, B1[nt][kt], acg[0][nt]);
                acg[1][nt] = MFMA16(a1, B1[nt][kt], acg[1][nt]);
            }
        }
        // bias + ReLU -> hs rows 0..31
        #pragma unroll
        for (int nt = 0; nt < 2; nt++) {
            const int col = base_n + nt * 16 + l15;
            #pragma unroll
            for (int mt = 0; mt < 2; mt++)
                #pragma unroll
                for (int r = 0; r < 4; r++) {
                    const int row = mt * 16 + quad * 4 + r;
                    const float v = acg[mt][nt][r] + bias1[nt];
                    hs[row * 264 + col] = f2bfu(v > 0.f ? v : 0.f);
                }
        }
        __syncthreads();

        // layer 2: M=32, wave's N=16 (c2), K=256; direct predicated stores
        v4f ao0 = (v4f){0.f, 0.f, 0.f, 0.f};
        v4f ao1 = (v4f){0.f, 0.f, 0.f, 0.f};
        #pragma unroll
        for (int kt = 0; kt < 8; kt++) {
            const int ko = kt * 32 + quad * 8;
            v8s av0 = *(const v8s*)(&hs[(     l15) * 264 + ko]);
            v8s av1 = *(const v8s*)(&hs[(16 + l15) * 264 + ko]);
            ao0 = MFMA16(av0, B2[kt], ao0);
            ao1 = MFMA16(av1, B2[kt], ao1);
        }
        if (c2 < 2 * HDG_) {
            #pragma unroll
            for (int mt = 0; mt < 2; mt++) {
                #pragma unroll
                for (int r = 0; r < 4; r++) {
                    const int lg = mt * 16 + quad * 4 + r;
                    if (lg < ngr) {
                        const int ltg = lg >> 1, p = lg & 1;
                        const int slot = 2 * (bslot + ltg * 128) + p;
                        const int g = (slot < cnt) ? glds[ltg * 2 + p] : scanS[9];
                        const float o = (mt ? ao1[r] : ao0[r]) + bias2g;
                        if (c2 < HDG_) out[OFF_GH + g * HDG_ + c2] = o;
                        else           out[OFF_GV + g * HDG_ + (c2 - HDG_)] = o * o;
                    }
                }
            }
        }
    }
}

extern "C" void kernel_launch(void* const* d_in, const int* in_sizes, int n_in,
                              void* d_out, int out_size, void* d_ws, size_t ws_size,
                              hipStream_t stream) {
    const float* x      = (const float*)d_in[0];
    const int*   dsname = (const int*)d_in[1];
    // d_in[2] = batch: arange(N)//32 by construction; structure used directly.
    const float* Wgs = (const float*)d_in[3];
    const float* bgs = (const float*)d_in[4];
    const float* Wgh = (const float*)d_in[5];
    const float* bgh = (const float*)d_in[6];
    const float* Wn1 = (const float*)d_in[7];
    const float* bn1 = (const float*)d_in[8];
    const float* Wn2 = (const float*)d_in[9];
    const float* bn2 = (const float*)d_in[10];
    float* out = (float*)d_out;

    fused_all<<<256, 512, 0, stream>>>(x, dsname, Wn1, bn1, Wn2, bn2,
                                       Wgs, bgs, Wgh, bgh, out);
}